// Round 7
// baseline (1287.424 us; speedup 1.0000x reference)
//
#include <hip/hip_runtime.h>
#include <math.h>
#include <stdint.h>

#define E_N 19
#define H_N 32
#define T_N 2048
#define B_N 64
#define G_N 128      // 4*H gate rows per chain
#define XCHUNK 64    // timesteps staged per register round
#define LOG2E 1.4426950408889634f

typedef _Float16 half2_t __attribute__((ext_vector_type(2)));

__device__ __forceinline__ float lanef(float v, int l) {
    return __int_as_float(__builtin_amdgcn_readlane(__float_as_int(v), l));
}
__device__ __forceinline__ uint32_t laneu(uint32_t v, int l) {
    return (uint32_t)__builtin_amdgcn_readlane((int)v, l);
}
__device__ __forceinline__ float sigm_rcp(float e) {  // 1/(1+e)
    return __builtin_amdgcn_rcpf(1.0f + e);
}

// One WAVE per chain (b, e, dir). ONE DS op per step, no barriers, no LDS.
// Lane pairing chosen so cross-lane traffic is minimal:
//   half0 lane j owns rows i_j (row j)    and g_j (row j+64): ig = i*g is LOCAL
//   half1 lane j owns rows f_j (row j+32) and o_j (row j+96): c,h update is LOCAL
// Per step: one shfl_xor(ig,32) moves ig to half1; c,h computed on half1
// (half0 runs the same instrs on garbage). h broadcast: v_cvt_f16 + 32
// readlanes from lanes 32..63, paired into 16 SGPRs by SALU (free).
__global__ __launch_bounds__(64)
__attribute__((amdgpu_waves_per_eu(3, 3)))
void lstm_chain_kernel(
    const float* __restrict__ x,     // [B, T, E]
    const float* __restrict__ w_ih,  // [E, 2, 4H]
    const float* __restrict__ w_hh,  // [E, 2, 4H, H]
    const float* __restrict__ b_ih,  // [E, 2, 4H]
    const float* __restrict__ b_hh,  // [E, 2, 4H]
    float* __restrict__ hT)          // [B, E, 2, H]
{
    const int lane  = threadIdx.x;
    const int chain = blockIdx.x;            // b*(E*2) + e*2 + d
    const int b  = chain / (E_N * 2);
    const int ed = chain - b * (E_N * 2);
    const int e  = ed >> 1;
    const int d  = ed & 1;
    const int j    = lane & 31;
    const int half = lane >> 5;

    const int r1 = j + 32 * half;        // i_j (half0) or f_j (half1) -> sigmoid
    const int r2 = j + 64 + 32 * half;   // g_j (half0, tanh) or o_j (half1, sigmoid)

    // ---- load fp32 weights, quantize to packed fp16 pairs (16+16 VGPRs) ----
    const float* wr1 = w_hh + ((size_t)ed * G_N + r1) * H_N;
    const float* wr2 = w_hh + ((size_t)ed * G_N + r2) * H_N;
    uint32_t w1p[16], w2p[16];
    #pragma unroll
    for (int m = 0; m < 16; ++m) {
        float2 v1 = ((const float2*)wr1)[m];
        float2 v2 = ((const float2*)wr2)[m];
        half2_t p1 = { (_Float16)v1.x, (_Float16)v1.y };
        half2_t p2 = { (_Float16)v2.x, (_Float16)v2.y };
        w1p[m] = __builtin_bit_cast(uint32_t, p1);
        w2p[m] = __builtin_bit_cast(uint32_t, p2);
    }

    const float wih1  = w_ih[(size_t)ed * G_N + r1];
    const float wih2  = w_ih[(size_t)ed * G_N + r2];
    const float bias1 = b_ih[(size_t)ed * G_N + r1] + b_hh[(size_t)ed * G_N + r1];
    const float bias2 = b_ih[(size_t)ed * G_N + r2] + b_hh[(size_t)ed * G_N + r2];

    // act2: half0 -> tanh(g) = 2*sigm(2g)-1 ; half1 -> sigmoid(o)
    const float K2 = half ? (-LOG2E) : (-2.0f * LOG2E);
    const float A2 = half ?  1.0f :  2.0f;
    const float B2 = half ?  0.0f : -1.0f;

    uint32_t sh[16];   // wave-uniform packed h pairs (SGPRs)
    #pragma unroll
    for (int m = 0; m < 16; ++m) sh[m] = 0u;

    float c = 0.0f;    // valid on half1
    float h = 0.0f;    // valid on half1

    const float* xbase = x + (size_t)b * T_N * E_N + e;

    for (int t0 = 0; t0 < T_N; t0 += XCHUNK) {
        // PIN: keep the 32 packed weight regs live across the inner loop (no-op).
        #pragma unroll
        for (int m = 0; m < 16; ++m) {
            asm volatile("" : "+v"(w1p[m]), "+v"(w2p[m]));
        }

        // stage 64 timesteps, one per lane (reversed time for d==1)
        const int tt    = t0 + lane;
        const int tphys = d ? (T_N - 1 - tt) : tt;
        const float xr  = xbase[(size_t)tphys * E_N];

        #pragma unroll 1
        for (int tl = 0; tl < XCHUNK; ++tl) {
            const float sx = lanef(xr, tl);          // wave-uniform x_t

            float a1 = fmaf(sx, wih1, bias1), a1b = 0.0f;
            float a2 = fmaf(sx, wih2, bias2), a2b = 0.0f;
            #pragma unroll
            for (int m = 0; m < 8; ++m) {
                a1  = __builtin_amdgcn_fdot2(__builtin_bit_cast(half2_t, sh[m]),
                                             __builtin_bit_cast(half2_t, w1p[m]),   a1,  false);
                a1b = __builtin_amdgcn_fdot2(__builtin_bit_cast(half2_t, sh[m+8]),
                                             __builtin_bit_cast(half2_t, w1p[m+8]), a1b, false);
                a2  = __builtin_amdgcn_fdot2(__builtin_bit_cast(half2_t, sh[m]),
                                             __builtin_bit_cast(half2_t, w2p[m]),   a2,  false);
                a2b = __builtin_amdgcn_fdot2(__builtin_bit_cast(half2_t, sh[m+8]),
                                             __builtin_bit_cast(half2_t, w2p[m+8]), a2b, false);
            }
            const float g1 = a1 + a1b;
            const float g2 = a2 + a2b;

            // act1: sigmoid on both halves (i_j / f_j)
            const float act1 = sigm_rcp(__builtin_amdgcn_exp2f(g1 * (-LOG2E)));
            // act2: tanh (half0: g_j) / sigmoid (half1: o_j)
            const float act2 = fmaf(A2, sigm_rcp(__builtin_amdgcn_exp2f(g2 * K2)), B2);

            const float ig  = act1 * act2;           // half0: i*g (valid); half1: f*o (junk)
            const float igx = __shfl_xor(ig, 32);    // half1 receives i*g   [the ONE DS op]

            // valid on half1 only (half0 computes garbage on same instructions)
            c = fmaf(act1, c, igx);                                  // f*c + i*g
            const float tc = fmaf(2.0f, sigm_rcp(
                __builtin_amdgcn_exp2f(c * (-2.0f * LOG2E))), -1.0f); // tanh(c)
            h = act2 * tc;                                           // o * tanh(c)

            // broadcast h: f32->f16 (low 16 bits), 32 readlanes from half1,
            // pack pairs with SALU (hidden behind VALU)
            const uint32_t hu = (uint32_t)__builtin_bit_cast(uint16_t, (_Float16)h);
            #pragma unroll
            for (int m = 0; m < 16; ++m) {
                const uint32_t lo = laneu(hu, 32 + 2 * m);
                const uint32_t hi = laneu(hu, 33 + 2 * m);
                sh[m] = lo | (hi << 16);
            }
        }
    }

    if (half) {
        hT[((size_t)(b * E_N + e) * 2 + d) * H_N + j] = h;
    }
}

// LayerNorm over 64 feats per (b,e), mean over e, FC -> out[b]. One wave per b.
__global__ __launch_bounds__(64) void head_kernel(
    const float* __restrict__ hT,      // [B, E, 64]
    const float* __restrict__ ln_gamma,// [E, 64]
    const float* __restrict__ ln_beta, // [E, 64]
    const float* __restrict__ fc_w,    // [64]
    const float* __restrict__ fc_b,    // [1]
    float* __restrict__ out)           // [B]
{
    const int b = blockIdx.x;
    const int f = threadIdx.x; // 0..63

    float acc = 0.0f;
    for (int e = 0; e < E_N; ++e) {
        const float v = hT[(size_t)(b * E_N + e) * 64 + f];
        float s = v, s2 = v * v;
        #pragma unroll
        for (int off = 32; off > 0; off >>= 1) {
            s  += __shfl_xor(s,  off);
            s2 += __shfl_xor(s2, off);
        }
        const float mean = s * (1.0f / 64.0f);
        const float var  = s2 * (1.0f / 64.0f) - mean * mean;
        const float inv  = rsqrtf(var + 1e-5f);
        acc += (v - mean) * inv * ln_gamma[e * 64 + f] + ln_beta[e * 64 + f];
    }
    float contrib = (acc * (1.0f / (float)E_N)) * fc_w[f];
    #pragma unroll
    for (int off = 32; off > 0; off >>= 1) contrib += __shfl_xor(contrib, off);
    if (f == 0) out[b] = contrib + fc_b[0];
}

extern "C" void kernel_launch(void* const* d_in, const int* in_sizes, int n_in,
                              void* d_out, int out_size, void* d_ws, size_t ws_size,
                              hipStream_t stream) {
    const float* x        = (const float*)d_in[0];
    const float* w_ih     = (const float*)d_in[1];
    const float* w_hh     = (const float*)d_in[2];
    const float* b_ih     = (const float*)d_in[3];
    const float* b_hh     = (const float*)d_in[4];
    const float* ln_gamma = (const float*)d_in[5];
    const float* ln_beta  = (const float*)d_in[6];
    const float* fc_w     = (const float*)d_in[7];
    const float* fc_b     = (const float*)d_in[8];
    float* out = (float*)d_out;
    float* hT  = (float*)d_ws;  // B*E*2*H floats

    lstm_chain_kernel<<<B_N * E_N * 2, 64, 0, stream>>>(x, w_ih, w_hh, b_ih, b_hh, hT);
    head_kernel<<<B_N, 64, 0, stream>>>(hT, ln_gamma, ln_beta, fc_w, fc_b, out);
}

// Round 8
// 897.379 us; speedup vs baseline: 1.4346x; 1.4346x over previous
//
#include <hip/hip_runtime.h>
#include <math.h>
#include <stdint.h>

#define E_N 19
#define H_N 32
#define T_N 2048
#define B_N 64
#define G_N 128      // 4*H gate rows per chain
#define XCHUNK 64    // timesteps staged per LDS round
#define LOG2E 1.4426950408889634f

typedef _Float16 half2_t __attribute__((ext_vector_type(2)));

__device__ __forceinline__ float sigm_rcp(float e) {  // 1/(1+e)
    return __builtin_amdgcn_rcpf(1.0f + e);
}

// One WAVE (one 64-thread block) per chain (b, e, dir). No barriers.
// Lane pairing (as R7): j = lane&31, half = lane>>5.
//   half0 lane j owns rows i_j (row j)    and g_j (row j+64): ig = i*g is LOCAL
//   half1 lane j owns rows f_j (row j+32) and o_j (row j+96): c,h update is LOCAL
// Cross-lane per step: ONE shfl_xor(ig,32). h broadcast via LDS:
// half1 ds_write_b16 h_j -> all lanes re-read 32 packed fp16 h as 4x ds_read_b128
// (same-address broadcast, conflict-free). x read from LDS (uniform b32).
__global__ __launch_bounds__(64)
__attribute__((amdgpu_waves_per_eu(3, 3)))
void lstm_chain_kernel(
    const float* __restrict__ x,     // [B, T, E]
    const float* __restrict__ w_ih,  // [E, 2, 4H]
    const float* __restrict__ w_hh,  // [E, 2, 4H, H]
    const float* __restrict__ b_ih,  // [E, 2, 4H]
    const float* __restrict__ b_hh,  // [E, 2, 4H]
    float* __restrict__ hT)          // [B, E, 2, H]
{
    const int lane  = threadIdx.x;
    const int chain = blockIdx.x;            // b*(E*2) + e*2 + d
    const int b  = chain / (E_N * 2);
    const int ed = chain - b * (E_N * 2);
    const int e  = ed >> 1;
    const int d  = ed & 1;
    const int j    = lane & 31;
    const int half = lane >> 5;

    const int r1 = j + 32 * half;        // i_j (half0) or f_j (half1) -> sigmoid
    const int r2 = j + 64 + 32 * half;   // g_j (half0, tanh) or o_j (half1, sigmoid)

    // ---- load fp32 weights, quantize to packed fp16 pairs (16+16 VGPRs) ----
    const float* wr1 = w_hh + ((size_t)ed * G_N + r1) * H_N;
    const float* wr2 = w_hh + ((size_t)ed * G_N + r2) * H_N;
    uint32_t w1p[16], w2p[16];
    #pragma unroll
    for (int m = 0; m < 16; ++m) {
        float2 v1 = ((const float2*)wr1)[m];
        float2 v2 = ((const float2*)wr2)[m];
        half2_t p1 = { (_Float16)v1.x, (_Float16)v1.y };
        half2_t p2 = { (_Float16)v2.x, (_Float16)v2.y };
        w1p[m] = __builtin_bit_cast(uint32_t, p1);
        w2p[m] = __builtin_bit_cast(uint32_t, p2);
    }

    const float wih1  = w_ih[(size_t)ed * G_N + r1];
    const float wih2  = w_ih[(size_t)ed * G_N + r2];
    const float bias1 = b_ih[(size_t)ed * G_N + r1] + b_hh[(size_t)ed * G_N + r1];
    const float bias2 = b_ih[(size_t)ed * G_N + r2] + b_hh[(size_t)ed * G_N + r2];

    // act2: half0 -> tanh(g) = 2*sigm(2g)-1 ; half1 -> sigmoid(o)
    const float K2 = half ? (-LOG2E) : (-2.0f * LOG2E);
    const float A2 = half ?  1.0f :  2.0f;
    const float B2 = half ?  0.0f : -1.0f;

    // LDS: h (32 fp16) + dummy write region (32 fp16) + x chunk (64 f32)
    __shared__ __align__(16) uint16_t hbuf[64];   // [0..31] real, [32..63] dummy
    __shared__ float xbuf[XCHUNK];

    if (lane < 32) hbuf[lane] = 0;      // zero real h slots
    float c = 0.0f;    // valid on half1
    float h = 0.0f;    // valid on half1

    const float* xbase = x + (size_t)b * T_N * E_N + e;
    // half1 writes real slot j, half0 writes dummy slot 32+j (branchless)
    const int hwr = j + 32 * (1 - half);

    for (int t0 = 0; t0 < T_N; t0 += XCHUNK) {
        // PIN: keep the 32 packed weight regs live across the inner loop (no-op).
        #pragma unroll
        for (int m = 0; m < 16; ++m) {
            asm volatile("" : "+v"(w1p[m]), "+v"(w2p[m]));
        }

        // stage 64 timesteps into LDS, one per lane (reversed time for d==1)
        const int tt    = t0 + lane;
        const int tphys = d ? (T_N - 1 - tt) : tt;
        xbuf[lane] = xbase[(size_t)tphys * E_N];

        #pragma unroll 1
        for (int tl = 0; tl < XCHUNK; ++tl) {
            // broadcast reads: 32 h fp16 (4 x b128) + x (uniform b32)
            const uint4 q0 = ((const uint4*)hbuf)[0];   // units 0..7
            const uint4 q1 = ((const uint4*)hbuf)[1];   // units 8..15
            const uint4 q2 = ((const uint4*)hbuf)[2];   // units 16..23
            const uint4 q3 = ((const uint4*)hbuf)[3];   // units 24..31
            const float sx = xbuf[tl];

            uint32_t hp[16];
            hp[0]=q0.x; hp[1]=q0.y; hp[2]=q0.z; hp[3]=q0.w;
            hp[4]=q1.x; hp[5]=q1.y; hp[6]=q1.z; hp[7]=q1.w;
            hp[8]=q2.x; hp[9]=q2.y; hp[10]=q2.z; hp[11]=q2.w;
            hp[12]=q3.x; hp[13]=q3.y; hp[14]=q3.z; hp[15]=q3.w;

            float a1 = fmaf(sx, wih1, bias1), a1b = 0.0f;
            float a2 = fmaf(sx, wih2, bias2), a2b = 0.0f;
            #pragma unroll
            for (int m = 0; m < 8; ++m) {
                a1  = __builtin_amdgcn_fdot2(__builtin_bit_cast(half2_t, hp[m]),
                                             __builtin_bit_cast(half2_t, w1p[m]),   a1,  false);
                a1b = __builtin_amdgcn_fdot2(__builtin_bit_cast(half2_t, hp[m+8]),
                                             __builtin_bit_cast(half2_t, w1p[m+8]), a1b, false);
                a2  = __builtin_amdgcn_fdot2(__builtin_bit_cast(half2_t, hp[m]),
                                             __builtin_bit_cast(half2_t, w2p[m]),   a2,  false);
                a2b = __builtin_amdgcn_fdot2(__builtin_bit_cast(half2_t, hp[m+8]),
                                             __builtin_bit_cast(half2_t, w2p[m+8]), a2b, false);
            }
            const float g1 = a1 + a1b;
            const float g2 = a2 + a2b;

            // act1: sigmoid on both halves (i_j / f_j)
            const float act1 = sigm_rcp(__builtin_amdgcn_exp2f(g1 * (-LOG2E)));
            // act2: tanh (half0: g_j) / sigmoid (half1: o_j)
            const float act2 = fmaf(A2, sigm_rcp(__builtin_amdgcn_exp2f(g2 * K2)), B2);

            const float ig  = act1 * act2;           // half0: i*g (valid); half1: f*o (junk)
            const float igx = __shfl_xor(ig, 32);    // half1 receives i*g   [one DS op]

            // valid on half1 only (half0 computes garbage on same instructions)
            c = fmaf(act1, c, igx);                                   // f*c + i*g
            const float tc = fmaf(2.0f, sigm_rcp(
                __builtin_amdgcn_exp2f(c * (-2.0f * LOG2E))), -1.0f); // tanh(c)
            h = act2 * tc;                                            // o * tanh(c)

            // publish h: half1 -> real slot j; half0 -> dummy slot (branchless)
            hbuf[hwr] = __builtin_bit_cast(uint16_t, (_Float16)h);
        }
    }

    if (half) {
        hT[((size_t)(b * E_N + e) * 2 + d) * H_N + j] = h;
    }
}

// LayerNorm over 64 feats per (b,e), mean over e, FC -> out[b]. One wave per b.
__global__ __launch_bounds__(64) void head_kernel(
    const float* __restrict__ hT,      // [B, E, 64]
    const float* __restrict__ ln_gamma,// [E, 64]
    const float* __restrict__ ln_beta, // [E, 64]
    const float* __restrict__ fc_w,    // [64]
    const float* __restrict__ fc_b,    // [1]
    float* __restrict__ out)           // [B]
{
    const int b = blockIdx.x;
    const int f = threadIdx.x; // 0..63

    float acc = 0.0f;
    for (int e = 0; e < E_N; ++e) {
        const float v = hT[(size_t)(b * E_N + e) * 64 + f];
        float s = v, s2 = v * v;
        #pragma unroll
        for (int off = 32; off > 0; off >>= 1) {
            s  += __shfl_xor(s,  off);
            s2 += __shfl_xor(s2, off);
        }
        const float mean = s * (1.0f / 64.0f);
        const float var  = s2 * (1.0f / 64.0f) - mean * mean;
        const float inv  = rsqrtf(var + 1e-5f);
        acc += (v - mean) * inv * ln_gamma[e * 64 + f] + ln_beta[e * 64 + f];
    }
    float contrib = (acc * (1.0f / (float)E_N)) * fc_w[f];
    #pragma unroll
    for (int off = 32; off > 0; off >>= 1) contrib += __shfl_xor(contrib, off);
    if (f == 0) out[b] = contrib + fc_b[0];
}

extern "C" void kernel_launch(void* const* d_in, const int* in_sizes, int n_in,
                              void* d_out, int out_size, void* d_ws, size_t ws_size,
                              hipStream_t stream) {
    const float* x        = (const float*)d_in[0];
    const float* w_ih     = (const float*)d_in[1];
    const float* w_hh     = (const float*)d_in[2];
    const float* b_ih     = (const float*)d_in[3];
    const float* b_hh     = (const float*)d_in[4];
    const float* ln_gamma = (const float*)d_in[5];
    const float* ln_beta  = (const float*)d_in[6];
    const float* fc_w     = (const float*)d_in[7];
    const float* fc_b     = (const float*)d_in[8];
    float* out = (float*)d_out;
    float* hT  = (float*)d_ws;  // B*E*2*H floats

    lstm_chain_kernel<<<B_N * E_N * 2, 64, 0, stream>>>(x, w_ih, w_hh, b_ih, b_hh, hT);
    head_kernel<<<B_N, 64, 0, stream>>>(hT, ln_gamma, ln_beta, fc_w, fc_b, out);
}